// Round 6
// baseline (499.585 us; speedup 1.0000x reference)
//
#include <hip/hip_runtime.h>
#include <stdint.h>

#define S_LEN 2048
#define HID 3584
#define NHEADS 28
#define NKVH 4
#define DHEAD 128

typedef __attribute__((ext_vector_type(8))) short short8;
typedef __attribute__((ext_vector_type(4))) float f32x4;

__device__ __forceinline__ uint16_t f2bf(float f) {
    uint32_t u = __float_as_uint(f);
    u += 0x7fffu + ((u >> 16) & 1u);   // RNE
    return (uint16_t)(u >> 16);
}

// async global->LDS DMA, 16B per lane; LDS dest = wave-uniform base + lane*16
__device__ __forceinline__ void gload16(const uint16_t* g, uint16_t* l) {
    __builtin_amdgcn_global_load_lds(
        (const __attribute__((address_space(1))) uint32_t*)g,
        (__attribute__((address_space(3))) uint32_t*)l, 16, 0, 0);
}

// ---------------- fused fp32 -> bf16 conversion (all 5 tensors, 1 launch) ----------------
#define C_HS 1835008
#define C_WQ 5046272
#define C_WK 5505024
#define C_WV 5963776
#define C_TOT 9175040
__global__ void cvt_all(const float* __restrict__ hs, const float* __restrict__ Wq,
                        const float* __restrict__ Wk, const float* __restrict__ Wv,
                        const float* __restrict__ Wo,
                        uint16_t* __restrict__ hs_bf, uint16_t* __restrict__ wqkv_bf,
                        uint16_t* __restrict__ wo_bf) {
    int i = blockIdx.x * 256 + threadIdx.x;
    if (i >= C_TOT) return;
    const float* src; uint16_t* dst; int off;
    if (i < C_HS)      { src = hs; dst = hs_bf;               off = i; }
    else if (i < C_WQ) { src = Wq; dst = wqkv_bf;             off = i - C_HS; }
    else if (i < C_WK) { src = Wk; dst = wqkv_bf + 12845056;  off = i - C_WQ; }
    else if (i < C_WV) { src = Wv; dst = wqkv_bf + 14680064;  off = i - C_WK; }
    else               { src = Wo; dst = wo_bf;               off = i - C_WV; }
    float4 f = ((const float4*)src)[off];
    uint2 v;
    v.x = (uint32_t)f2bf(f.x) | ((uint32_t)f2bf(f.y) << 16);
    v.y = (uint32_t)f2bf(f.z) | ((uint32_t)f2bf(f.w) << 16);
    *(uint2*)(dst + (size_t)off * 4) = v;
}

__global__ void concat_bias(const float* __restrict__ bq, const float* __restrict__ bk,
                            const float* __restrict__ bv, float* __restrict__ dst) {
    int i = blockIdx.x * 256 + threadIdx.x;
    if (i < 3584) dst[i] = bq[i];
    else if (i < 4096) dst[i] = bk[i - 3584];
    else if (i < 4608) dst[i] = bv[i - 4096];
}

// ---------------- bf16 GEMM, split-K=2: C(f32) += A * B^T ----------------
// 128x128 tile (R4 reuse ratio) x 2 K-halves (R5 residency): grid = 2*ntm*nt.
// sk outermost (each pass's working set ~24 MB <= aggregate L2), bn fastest
// within a pass (R4's empirically-best order, FETCH 122 MB).
// global_load_lds staging into XOR-swizzled unpadded LDS (conflict 0, R4-verified).
// Epilogue: unsafeAtomicAdd fp32 (hw global_atomic_add_f32; 2 commutative adds
// onto zeroed base -> deterministic). Bias/bf16-convert moved to consumers.
__global__ __launch_bounds__(256) void gemm_sk(const uint16_t* __restrict__ A,
                                               const uint16_t* __restrict__ B,
                                               float* __restrict__ C,
                                               int N, int K, int ldc)
{
    __shared__ __align__(16) uint16_t As[128 * 64];
    __shared__ __align__(16) uint16_t Bs[128 * 64];
    const int tid  = threadIdx.x;
    const int lane = tid & 63;
    const int w    = tid >> 6;
    const int quad = lane >> 4, l15 = lane & 15;
    const int sw   = l15 & 7;
    const int wr = w >> 1, wc = w & 1;

    const int nt = N >> 7;
    const int half = (int)gridDim.x >> 1;
    const int sk = ((int)blockIdx.x >= half) ? 1 : 0;
    const int id = (int)blockIdx.x - sk * half;
    const int bm = id / nt, bn = id % nt;      // bn fastest (R4 order)
    const int k0 = sk * (K >> 1);
    const int kend = k0 + (K >> 1);

    // DMA source addrs: wave w stages rows [w*32, +32) of each 128x64 tile.
    const uint16_t* Agp[4];
    const uint16_t* Bgp[4];
#pragma unroll
    for (int i = 0; i < 4; ++i) {
        int sg = i * 64 + lane;
        int rowl = sg >> 3;
        int g = (sg & 7) ^ (rowl & 7);
        int row = w * 32 + rowl;
        Agp[i] = A + (size_t)(bm * 128 + row) * K + g * 8;
        Bgp[i] = B + (size_t)(bn * 128 + row) * K + g * 8;
    }
    uint16_t* Asd = &As[w * 2048];
    uint16_t* Bsd = &Bs[w * 2048];

    f32x4 acc[4][4] = {};

    for (int kt = k0; kt < kend; kt += 64) {
        __syncthreads();                       // prev iter's LDS reads done
#pragma unroll
        for (int i = 0; i < 4; ++i) gload16(Agp[i] + kt, Asd + i * 512);
#pragma unroll
        for (int i = 0; i < 4; ++i) gload16(Bgp[i] + kt, Bsd + i * 512);
        __syncthreads();                       // DMA drained
#pragma unroll
        for (int ks = 0; ks < 2; ++ks) {
            const int co = ((ks * 4 + quad) ^ sw) * 8;   // swizzled granule offset
            short8 af[4], bf[4];
#pragma unroll
            for (int i = 0; i < 4; ++i)
                af[i] = *(const short8*)&As[(wr * 64 + i * 16 + l15) * 64 + co];
#pragma unroll
            for (int j = 0; j < 4; ++j)
                bf[j] = *(const short8*)&Bs[(wc * 64 + j * 16 + l15) * 64 + co];
#pragma unroll
            for (int i = 0; i < 4; ++i)
#pragma unroll
                for (int j = 0; j < 4; ++j)
                    acc[i][j] = __builtin_amdgcn_mfma_f32_16x16x32_bf16(af[i], bf[j], acc[i][j], 0, 0, 0);
        }
    }

    // C/D layout (verified m89/m91): row = quad*4 + r (A operand), col = lane&15 (B)
#pragma unroll
    for (int j = 0; j < 4; ++j) {
        const int col = bn * 128 + wc * 64 + j * 16 + l15;
#pragma unroll
        for (int i = 0; i < 4; ++i) {
#pragma unroll
            for (int r = 0; r < 4; ++r) {
                const int row = bm * 128 + wr * 64 + i * 16 + quad * 4 + r;
                unsafeAtomicAdd(&C[(size_t)row * ldc + col], acc[i][j][r]);
            }
        }
    }
}

// ---------------- M-RoPE + bias + repack to head-major (reads fp32 QKV) ----------------
__global__ void rope_pack(const float* __restrict__ qkv, const float* __restrict__ biasq,
                          const float* __restrict__ cosp, const float* __restrict__ sinp,
                          uint16_t* __restrict__ qr, uint16_t* __restrict__ kr)
{
    int idx = blockIdx.x * 256 + threadIdx.x;
    const int NQ = NHEADS * S_LEN * 64;
    const int NTOT = NQ + NKVH * S_LEN * 64;
    if (idx >= NTOT) return;
    bool isq = idx < NQ;
    int i = isq ? idx : idx - NQ;
    int d = i & 63;
    int s = (i >> 6) & (S_LEN - 1);
    int h = i >> 17;
    int col = (isq ? 0 : HID) + h * DHEAD + d;
    const float* rowp = qkv + (size_t)s * 4608;
    float x1 = rowp[col]      + biasq[col];
    float x2 = rowp[col + 64] + biasq[col + 64];
    int sec = d < 16 ? 0 : (d < 40 ? 1 : 2);
    size_t cb = (size_t)sec * (S_LEN * DHEAD) + (size_t)s * DHEAD + d;
    float c1 = cosp[cb],      s1 = sinp[cb];
    float c2 = cosp[cb + 64], s2 = sinp[cb + 64];
    float o1 = x1 * c1 - x2 * s1;
    float o2 = x2 * c2 + x1 * s2;
    uint16_t* dst = isq ? qr : kr;
    size_t ob = ((size_t)h * S_LEN + s) * DHEAD + d;
    dst[ob]      = f2bf(o1);
    dst[ob + 64] = f2bf(o2);
}

// ---------------- V: bias + transpose, fp32 qkv cols 4096.. -> vT [4][128][S] bf16 ----------------
__global__ void v_transpose(const float* __restrict__ qkv, const float* __restrict__ biasq,
                            uint16_t* __restrict__ vT)
{
    __shared__ __align__(16) uint16_t tile[64][68];
    const int tid = threadIdx.x;
    const int s0 = blockIdx.x * 64;
    const int n0 = blockIdx.y * 64;
    const int head = n0 >> 7, db = n0 & 127;
    const int rr = tid >> 4;
    const int c4 = (tid & 15) * 4;
    const float4 bb = *(const float4*)(biasq + 4096 + n0 + c4);
#pragma unroll
    for (int p = 0; p < 4; ++p) {
        int row = p * 16 + rr;
        float4 f = *(const float4*)(qkv + (size_t)(s0 + row) * 4608 + 4096 + n0 + c4);
        uint2 v;
        v.x = (uint32_t)f2bf(f.x + bb.x) | ((uint32_t)f2bf(f.y + bb.y) << 16);
        v.y = (uint32_t)f2bf(f.z + bb.z) | ((uint32_t)f2bf(f.w + bb.w) << 16);
        *(uint2*)&tile[row][c4] = v;
    }
    __syncthreads();
#pragma unroll
    for (int p = 0; p < 4; ++p) {
        int drow = p * 16 + rr;
        uint32_t a0 = tile[c4 + 0][drow];
        uint32_t a1 = tile[c4 + 1][drow];
        uint32_t a2 = tile[c4 + 2][drow];
        uint32_t a3 = tile[c4 + 3][drow];
        uint2 v; v.x = a0 | (a1 << 16); v.y = a2 | (a3 << 16);
        *(uint2*)(vT + (size_t)(head * 128 + db + drow) * S_LEN + s0 + c4) = v;
    }
}

// ---------------- flash attention (GQA, causal), S^T dataflow (frozen) ----------------
__global__ __launch_bounds__(256) void flash_attn(const uint16_t* __restrict__ qr,
                                                  const uint16_t* __restrict__ kr,
                                                  const uint16_t* __restrict__ vT,
                                                  uint16_t* __restrict__ out)
{
    __shared__ __align__(16) uint16_t Ks[64 * 128];    // [key][d], swizzled
    __shared__ __align__(16) uint16_t Vs[128 * 64];    // [d][key], swizzled
    __shared__ __align__(16) uint16_t Ps[4][16 * 72];  // per-wave P^T [qrow][key]
    const int tid = threadIdx.x;
    const int lane = tid & 63, w = tid >> 6;
    const int quad = lane >> 4, l15 = lane & 15;
    const int sw = l15 & 7;
    const int b = (int)blockIdx.x;
    const int qtp = b / 28;
    const int h = b - qtp * 28;
    const int qt = 31 - qtp;
    const int q0 = qt * 64;
    const int kvh = h / 7;
    const float SCL2 = 0.08838834764831845f * 1.44269504088896f;

    short8 qf[4];
    {
        const uint16_t* qb = qr + ((size_t)h * S_LEN + q0 + w * 16 + l15) * DHEAD;
#pragma unroll
        for (int ks = 0; ks < 4; ++ks)
            qf[ks] = *(const short8*)(qb + ks * 32 + quad * 8);
    }

    const uint16_t* Kgp[4];
    const uint16_t* Vgp[4];
    {
        const uint16_t* kbase = kr + (size_t)kvh * S_LEN * DHEAD;
        const uint16_t* vbase = vT + (size_t)kvh * DHEAD * S_LEN;
#pragma unroll
        for (int i = 0; i < 4; ++i) {
            int sg = w * 256 + i * 64 + lane;
            int rowk = sg >> 4;
            int gk = (sg & 8) | ((sg ^ rowk) & 7);
            Kgp[i] = kbase + (size_t)rowk * DHEAD + gk * 8;
            int rowv = sg >> 3;
            int gv = (sg ^ rowv) & 7;
            Vgp[i] = vbase + (size_t)rowv * S_LEN + gv * 8;
        }
    }
    uint16_t* Ksd = &Ks[w * 2048];
    uint16_t* Vsd = &Vs[w * 2048];

    f32x4 o[8] = {};
    float m_i = -1.0e30f, l_i = 0.0f;

    for (int kt = 0; kt <= qt; ++kt) {
        const int offk = kt * 64 * DHEAD;
        const int offv = kt * 64;
        __syncthreads();
#pragma unroll
        for (int i = 0; i < 4; ++i) gload16(Kgp[i] + offk, Ksd + i * 512);
#pragma unroll
        for (int i = 0; i < 4; ++i) gload16(Vgp[i] + offv, Vsd + i * 512);
        __syncthreads();

        f32x4 sc[4] = {};
#pragma unroll
        for (int j = 0; j < 4; ++j)
#pragma unroll
            for (int ks = 0; ks < 4; ++ks) {
                int g = ks * 4 + quad;
                int gp = (g & 8) | ((g ^ sw) & 7);
                short8 kf = *(const short8*)&Ks[(j * 16 + l15) * 128 + gp * 8];
                sc[j] = __builtin_amdgcn_mfma_f32_16x16x32_bf16(kf, qf[ks], sc[j], 0, 0, 0);
            }

        if (kt == qt) {
            int qrel = w * 16 + l15;
#pragma unroll
            for (int j = 0; j < 4; ++j)
#pragma unroll
                for (int r = 0; r < 4; ++r) {
                    int krel = j * 16 + quad * 4 + r;
                    sc[j][r] = (krel <= qrel) ? sc[j][r] * SCL2 : -1.0e30f;
                }
        } else {
#pragma unroll
            for (int j = 0; j < 4; ++j)
#pragma unroll
                for (int r = 0; r < 4; ++r) sc[j][r] *= SCL2;
        }

        float mx;
        {
            float m0 = fmaxf(fmaxf(sc[0][0], sc[0][1]), fmaxf(sc[0][2], sc[0][3]));
            float m1 = fmaxf(fmaxf(sc[1][0], sc[1][1]), fmaxf(sc[1][2], sc[1][3]));
            float m2 = fmaxf(fmaxf(sc[2][0], sc[2][1]), fmaxf(sc[2][2], sc[2][3]));
            float m3 = fmaxf(fmaxf(sc[3][0], sc[3][1]), fmaxf(sc[3][2], sc[3][3]));
            mx = fmaxf(fmaxf(m0, m1), fmaxf(m2, m3));
        }
        mx = fmaxf(mx, __shfl_xor(mx, 16));
        mx = fmaxf(mx, __shfl_xor(mx, 32));
        float mn = fmaxf(m_i, mx);
        float alpha = exp2f(m_i - mn);
        m_i = mn;
        float s = 0.0f;
#pragma unroll
        for (int j = 0; j < 4; ++j)
#pragma unroll
            for (int r = 0; r < 4; ++r) {
                float p = exp2f(sc[j][r] - mn);
                sc[j][r] = p;
                s += p;
            }
        s += __shfl_xor(s, 16);
        s += __shfl_xor(s, 32);
        l_i = l_i * alpha + s;
#pragma unroll
        for (int jd = 0; jd < 8; ++jd)
#pragma unroll
            for (int r = 0; r < 4; ++r) o[jd][r] *= alpha;

#pragma unroll
        for (int j = 0; j < 4; ++j) {
            uint2 p2;
            p2.x = (uint32_t)f2bf(sc[j][0]) | ((uint32_t)f2bf(sc[j][1]) << 16);
            p2.y = (uint32_t)f2bf(sc[j][2]) | ((uint32_t)f2bf(sc[j][3]) << 16);
            *(uint2*)&Ps[w][l15 * 72 + j * 16 + quad * 4] = p2;
        }

#pragma unroll
        for (int k2 = 0; k2 < 2; ++k2) {
            short8 pf = *(const short8*)&Ps[w][l15 * 72 + k2 * 32 + quad * 8];
#pragma unroll
            for (int jd = 0; jd < 8; ++jd) {
                int g = k2 * 4 + quad;
                int gp = (g ^ sw) & 7;
                short8 vf = *(const short8*)&Vs[(jd * 16 + l15) * 64 + gp * 8];
                o[jd] = __builtin_amdgcn_mfma_f32_16x16x32_bf16(vf, pf, o[jd], 0, 0, 0);
            }
        }
    }

    float inv = 1.0f / l_i;
    uint16_t* ob = out + (size_t)(q0 + w * 16 + l15) * HID + h * DHEAD + quad * 4;
#pragma unroll
    for (int jd = 0; jd < 8; ++jd) {
        uint2 p2;
        p2.x = (uint32_t)f2bf(o[jd][0] * inv) | ((uint32_t)f2bf(o[jd][1] * inv) << 16);
        p2.y = (uint32_t)f2bf(o[jd][2] * inv) | ((uint32_t)f2bf(o[jd][3] * inv) << 16);
        *(uint2*)(ob + jd * 16) = p2;
    }
}

// ---------------- launch ----------------
extern "C" void kernel_launch(void* const* d_in, const int* in_sizes, int n_in,
                              void* d_out, int out_size, void* d_ws, size_t ws_size,
                              hipStream_t stream)
{
    const float* hs   = (const float*)d_in[0];
    const float* Wq   = (const float*)d_in[1];
    const float* bq   = (const float*)d_in[2];
    const float* Wk   = (const float*)d_in[3];
    const float* bk   = (const float*)d_in[4];
    const float* Wv   = (const float*)d_in[5];
    const float* bv   = (const float*)d_in[6];
    const float* Wo   = (const float*)d_in[7];
    const float* cosp = (const float*)d_in[8];
    const float* sinp = (const float*)d_in[9];

    char* ws = (char*)d_ws;
    // Aliases (stream-ordered, non-overlapping lifetimes):
    //   qr aliases hs_bf (hs_bf dead after QKV GEMM; rope_pack writes qr after)
    //   attn_out aliases qkv_f32 (qkv_f32 dead after rope_pack+v_transpose)
    uint16_t* hs_bf   = (uint16_t*)(ws + 0);           // 2048*3584 bf16 (14.68 MB)
    uint16_t* qr      = (uint16_t*)(ws + 0);           // 28*2048*128 bf16 (alias)
    uint16_t* wqkv_bf = (uint16_t*)(ws + 14680064);    // 4608*3584 bf16 (33.03 MB)
    uint16_t* wo_bf   = (uint16_t*)(ws + 47710208);    // 3584*3584 bf16 (25.69 MB)
    float*    qkv_f32 = (float*)   (ws + 73400320);    // 2048*4608 f32 (37.75 MB)
    uint16_t* attn_out= (uint16_t*)(ws + 73400320);    // 2048*3584 bf16 (alias)
    uint16_t* kr      = (uint16_t*)(ws + 111149056);   // 4*2048*128 bf16 (2.10 MB)
    uint16_t* vT      = (uint16_t*)(ws + 113246208);   // 4*128*2048 bf16 (2.10 MB)
    float*    biasq   = (float*)   (ws + 115343360);   // 4608 f32

    hipMemsetAsync(qkv_f32, 0, 37748736, stream);
    hipMemsetAsync(d_out, 0, (size_t)out_size * sizeof(float), stream);

    cvt_all<<<35840, 256, 0, stream>>>(hs, Wq, Wk, Wv, Wo, hs_bf, wqkv_bf, wo_bf);
    concat_bias<<<18, 256, 0, stream>>>(bq, bk, bv, biasq);

    // QKV projection: split-K=2, grid 2 x 16 x 36 = 1152 blocks (4.5/CU)
    gemm_sk<<<2 * 16 * 36, 256, 0, stream>>>(hs_bf, wqkv_bf, qkv_f32, 4608, 3584, 4608);

    rope_pack<<<16384, 256, 0, stream>>>(qkv_f32, biasq, cosp, sinp, qr, kr);
    v_transpose<<<dim3(32, 8), 256, 0, stream>>>(qkv_f32, biasq, vT);

    flash_attn<<<896, 256, 0, stream>>>(qr, kr, vT, attn_out);

    // output projection: split-K=2, grid 2 x 16 x 28 = 896 blocks (3.5/CU)
    gemm_sk<<<2 * 16 * 28, 256, 0, stream>>>(attn_out, wo_bf, (float*)d_out, 3584, 3584, 3584);
}

// Round 7
// 452.275 us; speedup vs baseline: 1.1046x; 1.1046x over previous
//
#include <hip/hip_runtime.h>
#include <stdint.h>

#define S_LEN 2048
#define HID 3584
#define NHEADS 28
#define NKVH 4
#define DHEAD 128

typedef __attribute__((ext_vector_type(8))) short short8;
typedef __attribute__((ext_vector_type(4))) float f32x4;

__device__ __forceinline__ uint16_t f2bf(float f) {
    uint32_t u = __float_as_uint(f);
    u += 0x7fffu + ((u >> 16) & 1u);   // RNE
    return (uint16_t)(u >> 16);
}

// async global->LDS DMA, 16B per lane; LDS dest = wave-uniform base + lane*16
__device__ __forceinline__ void gload16(const uint16_t* g, uint16_t* l) {
    __builtin_amdgcn_global_load_lds(
        (const __attribute__((address_space(1))) uint32_t*)g,
        (__attribute__((address_space(3))) uint32_t*)l, 16, 0, 0);
}

// ---------------- fused fp32 -> bf16 conversion (all 5 tensors, 1 launch) ----------------
#define C_HS 1835008
#define C_WQ 5046272
#define C_WK 5505024
#define C_WV 5963776
#define C_TOT 9175040
__global__ void cvt_all(const float* __restrict__ hs, const float* __restrict__ Wq,
                        const float* __restrict__ Wk, const float* __restrict__ Wv,
                        const float* __restrict__ Wo,
                        uint16_t* __restrict__ hs_bf, uint16_t* __restrict__ wqkv_bf,
                        uint16_t* __restrict__ wo_bf) {
    int i = blockIdx.x * 256 + threadIdx.x;
    if (i >= C_TOT) return;
    const float* src; uint16_t* dst; int off;
    if (i < C_HS)      { src = hs; dst = hs_bf;               off = i; }
    else if (i < C_WQ) { src = Wq; dst = wqkv_bf;             off = i - C_HS; }
    else if (i < C_WK) { src = Wk; dst = wqkv_bf + 12845056;  off = i - C_WQ; }
    else if (i < C_WV) { src = Wv; dst = wqkv_bf + 14680064;  off = i - C_WK; }
    else               { src = Wo; dst = wo_bf;               off = i - C_WV; }
    float4 f = ((const float4*)src)[off];
    uint2 v;
    v.x = (uint32_t)f2bf(f.x) | ((uint32_t)f2bf(f.y) << 16);
    v.y = (uint32_t)f2bf(f.z) | ((uint32_t)f2bf(f.w) << 16);
    *(uint2*)(dst + (size_t)off * 4) = v;
}

__global__ void concat_bias(const float* __restrict__ bq, const float* __restrict__ bk,
                            const float* __restrict__ bv, float* __restrict__ dst) {
    int i = blockIdx.x * 256 + threadIdx.x;
    if (i < 3584) dst[i] = bq[i];
    else if (i < 4096) dst[i] = bk[i - 3584];
    else if (i < 4608) dst[i] = bv[i - 4096];
}

// ---------------- bf16 GEMM: C = A * B^T (+bias), double-buffered pipeline ----------------
// 128x128 tile, BK=64, XOR-swizzled unpadded LDS (conflict-free, R4-verified),
// global_load_lds staging. DOUBLE-BUFFERED: one barrier per iteration; DMA for
// tile k+1 is issued right after the barrier and drains at the NEXT barrier,
// so the global latency is covered by the compute phase instead of being
// exposed (the R4-R6 structure drained the DMA immediately -> ~500 TF plateau
// at 2-3 blocks/CU residency).
template <bool OUT_F32>
__global__ __launch_bounds__(256) void gemm_bt(const uint16_t* __restrict__ A,
                                               const uint16_t* __restrict__ B,
                                               const float* __restrict__ bias,
                                               void* __restrict__ C,
                                               int N, int K, int ldc)
{
    __shared__ __align__(16) uint16_t As[2][128 * 64];   // 2 x 16 KB
    __shared__ __align__(16) uint16_t Bs[2][128 * 64];   // 2 x 16 KB
    const int tid  = threadIdx.x;
    const int lane = tid & 63;
    const int w    = tid >> 6;
    const int quad = lane >> 4, l15 = lane & 15;
    const int sw   = l15 & 7;
    const int wr = w >> 1, wc = w & 1;
    const int nt = N >> 7;
    const int bm = (int)blockIdx.x / nt, bn = (int)blockIdx.x % nt;  // bn fastest (R4 order)

    // DMA source addrs: wave w stages rows [w*32, +32) of each 128x64 tile.
    // Granule g of row r stored at physical granule g^(r&7).
    const uint16_t* Agp[4];
    const uint16_t* Bgp[4];
#pragma unroll
    for (int i = 0; i < 4; ++i) {
        int sg = i * 64 + lane;
        int rowl = sg >> 3;
        int g = (sg & 7) ^ (rowl & 7);
        int row = w * 32 + rowl;
        Agp[i] = A + (size_t)(bm * 128 + row) * K + g * 8;
        Bgp[i] = B + (size_t)(bn * 128 + row) * K + g * 8;
    }
    const int ldsoff = w * 2048;   // wave's slice base within a buffer

    f32x4 acc[4][4] = {};

    // prologue: stage tile 0 into buffer 0
#pragma unroll
    for (int i = 0; i < 4; ++i) gload16(Agp[i], &As[0][ldsoff] + i * 512);
#pragma unroll
    for (int i = 0; i < 4; ++i) gload16(Bgp[i], &Bs[0][ldsoff] + i * 512);

    int buf = 0;
    for (int kt = 0; kt < K; kt += 64) {
        __syncthreads();   // drains DMA(buf) -> tile kt readable; prev reads of buf^1 done
        if (kt + 64 < K) { // prefetch tile kt+1 into buf^1; drains at NEXT barrier
#pragma unroll
            for (int i = 0; i < 4; ++i) gload16(Agp[i] + kt + 64, &As[buf ^ 1][ldsoff] + i * 512);
#pragma unroll
            for (int i = 0; i < 4; ++i) gload16(Bgp[i] + kt + 64, &Bs[buf ^ 1][ldsoff] + i * 512);
        }
        const uint16_t* Ac = &As[buf][0];
        const uint16_t* Bc = &Bs[buf][0];
#pragma unroll
        for (int ks = 0; ks < 2; ++ks) {
            const int co = ((ks * 4 + quad) ^ sw) * 8;   // swizzled granule offset
            short8 af[4], bf[4];
#pragma unroll
            for (int i = 0; i < 4; ++i)
                af[i] = *(const short8*)&Ac[(wr * 64 + i * 16 + l15) * 64 + co];
#pragma unroll
            for (int j = 0; j < 4; ++j)
                bf[j] = *(const short8*)&Bc[(wc * 64 + j * 16 + l15) * 64 + co];
#pragma unroll
            for (int i = 0; i < 4; ++i)
#pragma unroll
                for (int j = 0; j < 4; ++j)
                    acc[i][j] = __builtin_amdgcn_mfma_f32_16x16x32_bf16(af[i], bf[j], acc[i][j], 0, 0, 0);
        }
        buf ^= 1;
    }

    // C/D layout (verified m89/m91): row = quad*4 + r (A operand), col = lane&15 (B)
#pragma unroll
    for (int j = 0; j < 4; ++j) {
        const int col = bn * 128 + wc * 64 + j * 16 + l15;
        float bv = 0.0f;
        if constexpr (!OUT_F32) bv = bias[col];
#pragma unroll
        for (int i = 0; i < 4; ++i) {
#pragma unroll
            for (int r = 0; r < 4; ++r) {
                const int row = bm * 128 + wr * 64 + i * 16 + quad * 4 + r;
                const float v = acc[i][j][r] + bv;
                if constexpr (OUT_F32)
                    ((float*)C)[(size_t)row * ldc + col] = v;
                else
                    ((uint16_t*)C)[(size_t)row * ldc + col] = f2bf(v);
            }
        }
    }
}

// ---------------- M-RoPE + repack to head-major (bf16 qkv, bias already added) ----------------
__global__ void rope_pack(const uint16_t* __restrict__ qkv,
                          const float* __restrict__ cosp, const float* __restrict__ sinp,
                          uint16_t* __restrict__ qr, uint16_t* __restrict__ kr)
{
    int idx = blockIdx.x * 256 + threadIdx.x;
    const int NQ = NHEADS * S_LEN * 64;
    const int NTOT = NQ + NKVH * S_LEN * 64;
    if (idx >= NTOT) return;
    bool isq = idx < NQ;
    int i = isq ? idx : idx - NQ;
    int d = i & 63;
    int s = (i >> 6) & (S_LEN - 1);
    int h = i >> 17;
    int col = (isq ? 0 : HID) + h * DHEAD + d;
    const uint16_t* rowp = qkv + (size_t)s * 4608;
    float x1 = __uint_as_float(((uint32_t)rowp[col]) << 16);
    float x2 = __uint_as_float(((uint32_t)rowp[col + 64]) << 16);
    int sec = d < 16 ? 0 : (d < 40 ? 1 : 2);
    size_t cb = (size_t)sec * (S_LEN * DHEAD) + (size_t)s * DHEAD + d;
    float c1 = cosp[cb],      s1 = sinp[cb];
    float c2 = cosp[cb + 64], s2 = sinp[cb + 64];
    float o1 = x1 * c1 - x2 * s1;
    float o2 = x2 * c2 + x1 * s2;
    uint16_t* dst = isq ? qr : kr;
    size_t ob = ((size_t)h * S_LEN + s) * DHEAD + d;
    dst[ob]      = f2bf(o1);
    dst[ob + 64] = f2bf(o2);
}

// ---------------- V transpose: qkv[S][4608] cols 4096.. -> vT [4][128][S] ----------------
__global__ void v_transpose(const uint16_t* __restrict__ qkv, uint16_t* __restrict__ vT)
{
    __shared__ __align__(16) uint16_t tile[64][68];
    const int tid = threadIdx.x;
    const int s0 = blockIdx.x * 64;
    const int n0 = blockIdx.y * 64;
    const int head = n0 >> 7, db = n0 & 127;
    const int rr = tid >> 4;
    const int c4 = (tid & 15) * 4;
#pragma unroll
    for (int p = 0; p < 4; ++p) {
        int row = p * 16 + rr;
        uint2 v = *(const uint2*)(qkv + (size_t)(s0 + row) * 4608 + 4096 + n0 + c4);
        *(uint2*)&tile[row][c4] = v;
    }
    __syncthreads();
#pragma unroll
    for (int p = 0; p < 4; ++p) {
        int drow = p * 16 + rr;
        uint32_t a0 = tile[c4 + 0][drow];
        uint32_t a1 = tile[c4 + 1][drow];
        uint32_t a2 = tile[c4 + 2][drow];
        uint32_t a3 = tile[c4 + 3][drow];
        uint2 v; v.x = a0 | (a1 << 16); v.y = a2 | (a3 << 16);
        *(uint2*)(vT + (size_t)(head * 128 + db + drow) * S_LEN + s0 + c4) = v;
    }
}

// ---------------- flash attention (GQA, causal), S^T dataflow, double-buffered KV ----------------
// One barrier per KV tile: DMA for tile kt+1 issued after the barrier, drains
// at the next barrier (KV latency covered by QK+softmax+PV compute).
__global__ __launch_bounds__(256) void flash_attn(const uint16_t* __restrict__ qr,
                                                  const uint16_t* __restrict__ kr,
                                                  const uint16_t* __restrict__ vT,
                                                  uint16_t* __restrict__ out)
{
    __shared__ __align__(16) uint16_t Ks[2][64 * 128];   // [key][d], swizzled, 2 x 16 KB
    __shared__ __align__(16) uint16_t Vs[2][128 * 64];   // [d][key], swizzled, 2 x 16 KB
    __shared__ __align__(16) uint16_t Ps[4][16 * 72];    // per-wave P^T [qrow][key]
    const int tid = threadIdx.x;
    const int lane = tid & 63, w = tid >> 6;
    const int quad = lane >> 4, l15 = lane & 15;
    const int sw = l15 & 7;
    const int b = (int)blockIdx.x;
    const int qtp = b / 28;                  // heavy-first
    const int h = b - qtp * 28;
    const int qt = 31 - qtp;
    const int q0 = qt * 64;
    const int kvh = h / 7;                   // N_REP = 7
    const float SCL2 = 0.08838834764831845f * 1.44269504088896f;

    short8 qf[4];
    {
        const uint16_t* qb = qr + ((size_t)h * S_LEN + q0 + w * 16 + l15) * DHEAD;
#pragma unroll
        for (int ks = 0; ks < 4; ++ks)
            qf[ks] = *(const short8*)(qb + ks * 32 + quad * 8);
    }

    const uint16_t* Kgp[4];
    const uint16_t* Vgp[4];
    {
        const uint16_t* kbase = kr + (size_t)kvh * S_LEN * DHEAD;
        const uint16_t* vbase = vT + (size_t)kvh * DHEAD * S_LEN;
#pragma unroll
        for (int i = 0; i < 4; ++i) {
            int sg = w * 256 + i * 64 + lane;
            int rowk = sg >> 4;
            int gk = (sg & 8) | ((sg ^ rowk) & 7);
            Kgp[i] = kbase + (size_t)rowk * DHEAD + gk * 8;
            int rowv = sg >> 3;
            int gv = (sg ^ rowv) & 7;
            Vgp[i] = vbase + (size_t)rowv * S_LEN + gv * 8;
        }
    }
    const int ksoff = w * 2048;

    f32x4 o[8] = {};
    float m_i = -1.0e30f, l_i = 0.0f;

    // prologue: stage KV tile 0 into buffer 0
#pragma unroll
    for (int i = 0; i < 4; ++i) gload16(Kgp[i], &Ks[0][ksoff] + i * 512);
#pragma unroll
    for (int i = 0; i < 4; ++i) gload16(Vgp[i], &Vs[0][ksoff] + i * 512);

    int buf = 0;
    for (int kt = 0; kt <= qt; ++kt) {
        __syncthreads();                      // drains DMA(buf); prev reads of buf^1 done
        if (kt < qt) {                        // prefetch next KV tile into buf^1
            const int offk = (kt + 1) * 64 * DHEAD;
            const int offv = (kt + 1) * 64;
#pragma unroll
            for (int i = 0; i < 4; ++i) gload16(Kgp[i] + offk, &Ks[buf ^ 1][ksoff] + i * 512);
#pragma unroll
            for (int i = 0; i < 4; ++i) gload16(Vgp[i] + offv, &Vs[buf ^ 1][ksoff] + i * 512);
        }
        const uint16_t* Kc = &Ks[buf][0];
        const uint16_t* Vc = &Vs[buf][0];

        // S^T = K Q^T : D[key on quad*4+r][qrow on l15]
        f32x4 sc[4] = {};
#pragma unroll
        for (int j = 0; j < 4; ++j)
#pragma unroll
            for (int ks = 0; ks < 4; ++ks) {
                int g = ks * 4 + quad;
                int gp = (g & 8) | ((g ^ sw) & 7);
                short8 kf = *(const short8*)&Kc[(j * 16 + l15) * 128 + gp * 8];
                sc[j] = __builtin_amdgcn_mfma_f32_16x16x32_bf16(kf, qf[ks], sc[j], 0, 0, 0);
            }

        // scale (base-2) + causal mask (diag tile only)
        if (kt == qt) {
            int qrel = w * 16 + l15;
#pragma unroll
            for (int j = 0; j < 4; ++j)
#pragma unroll
                for (int r = 0; r < 4; ++r) {
                    int krel = j * 16 + quad * 4 + r;
                    sc[j][r] = (krel <= qrel) ? sc[j][r] * SCL2 : -1.0e30f;
                }
        } else {
#pragma unroll
            for (int j = 0; j < 4; ++j)
#pragma unroll
                for (int r = 0; r < 4; ++r) sc[j][r] *= SCL2;
        }

        // row max: in-register tree, then cross-quad (xor16, xor32)
        float mx;
        {
            float m0 = fmaxf(fmaxf(sc[0][0], sc[0][1]), fmaxf(sc[0][2], sc[0][3]));
            float m1 = fmaxf(fmaxf(sc[1][0], sc[1][1]), fmaxf(sc[1][2], sc[1][3]));
            float m2 = fmaxf(fmaxf(sc[2][0], sc[2][1]), fmaxf(sc[2][2], sc[2][3]));
            float m3 = fmaxf(fmaxf(sc[3][0], sc[3][1]), fmaxf(sc[3][2], sc[3][3]));
            mx = fmaxf(fmaxf(m0, m1), fmaxf(m2, m3));
        }
        mx = fmaxf(mx, __shfl_xor(mx, 16));
        mx = fmaxf(mx, __shfl_xor(mx, 32));
        float mn = fmaxf(m_i, mx);
        float alpha = exp2f(m_i - mn);
        m_i = mn;
        float s = 0.0f;
#pragma unroll
        for (int j = 0; j < 4; ++j)
#pragma unroll
            for (int r = 0; r < 4; ++r) {
                float p = exp2f(sc[j][r] - mn);
                sc[j][r] = p;
                s += p;
            }
        s += __shfl_xor(s, 16);
        s += __shfl_xor(s, 32);
        l_i = l_i * alpha + s;
#pragma unroll
        for (int jd = 0; jd < 8; ++jd)
#pragma unroll
            for (int r = 0; r < 4; ++r) o[jd][r] *= alpha;

        // pack P^T[qrow][key] (per-wave buf, same-wave LDS ordering)
#pragma unroll
        for (int j = 0; j < 4; ++j) {
            uint2 p2;
            p2.x = (uint32_t)f2bf(sc[j][0]) | ((uint32_t)f2bf(sc[j][1]) << 16);
            p2.y = (uint32_t)f2bf(sc[j][2]) | ((uint32_t)f2bf(sc[j][3]) << 16);
            *(uint2*)&Ps[w][l15 * 72 + j * 16 + quad * 4] = p2;
        }

        // O^T += V^T P^T
#pragma unroll
        for (int k2 = 0; k2 < 2; ++k2) {
            short8 pf = *(const short8*)&Ps[w][l15 * 72 + k2 * 32 + quad * 8];
#pragma unroll
            for (int jd = 0; jd < 8; ++jd) {
                int g = k2 * 4 + quad;
                int gp = (g ^ sw) & 7;
                short8 vf = *(const short8*)&Vc[(jd * 16 + l15) * 64 + gp * 8];
                o[jd] = __builtin_amdgcn_mfma_f32_16x16x32_bf16(vf, pf, o[jd], 0, 0, 0);
            }
        }
        buf ^= 1;
    }

    float inv = 1.0f / l_i;
    uint16_t* ob = out + (size_t)(q0 + w * 16 + l15) * HID + h * DHEAD + quad * 4;
#pragma unroll
    for (int jd = 0; jd < 8; ++jd) {
        uint2 p2;
        p2.x = (uint32_t)f2bf(o[jd][0] * inv) | ((uint32_t)f2bf(o[jd][1] * inv) << 16);
        p2.y = (uint32_t)f2bf(o[jd][2] * inv) | ((uint32_t)f2bf(o[jd][3] * inv) << 16);
        *(uint2*)(ob + jd * 16) = p2;
    }
}

// ---------------- launch ----------------
extern "C" void kernel_launch(void* const* d_in, const int* in_sizes, int n_in,
                              void* d_out, int out_size, void* d_ws, size_t ws_size,
                              hipStream_t stream)
{
    const float* hs   = (const float*)d_in[0];
    const float* Wq   = (const float*)d_in[1];
    const float* bq   = (const float*)d_in[2];
    const float* Wk   = (const float*)d_in[3];
    const float* bk   = (const float*)d_in[4];
    const float* Wv   = (const float*)d_in[5];
    const float* bv   = (const float*)d_in[6];
    const float* Wo   = (const float*)d_in[7];
    const float* cosp = (const float*)d_in[8];
    const float* sinp = (const float*)d_in[9];

    char* ws = (char*)d_ws;
    uint16_t* hs_bf   = (uint16_t*)(ws + 0);           // 2048*3584 bf16
    uint16_t* wqkv_bf = (uint16_t*)(ws + 14680064);    // 4608*3584 bf16
    uint16_t* wo_bf   = (uint16_t*)(ws + 47710208);    // 3584*3584 bf16
    uint16_t* qkv_buf = (uint16_t*)(ws + 73400320);    // 2048*4608 bf16; later attn_out
    uint16_t* qr      = (uint16_t*)(ws + 92274688);    // 28*2048*128 bf16
    uint16_t* kr      = (uint16_t*)(ws + 106954752);   // 4*2048*128 bf16
    uint16_t* vT      = (uint16_t*)(ws + 109051904);   // 4*128*2048 bf16
    float*    biasq   = (float*)(ws + 111149056);      // 4608 f32

    cvt_all<<<35840, 256, 0, stream>>>(hs, Wq, Wk, Wv, Wo, hs_bf, wqkv_bf, wo_bf);
    concat_bias<<<18, 256, 0, stream>>>(bq, bk, bv, biasq);

    // QKV projection: 16x36 = 576 blocks, double-buffered K-loop
    gemm_bt<false><<<16 * 36, 256, 0, stream>>>(hs_bf, wqkv_bf, biasq, qkv_buf, 4608, 3584, 4608);

    rope_pack<<<16384, 256, 0, stream>>>(qkv_buf, cosp, sinp, qr, kr);
    v_transpose<<<dim3(32, 8), 256, 0, stream>>>(qkv_buf, vT);

    flash_attn<<<896, 256, 0, stream>>>(qr, kr, vT, qkv_buf);

    // output projection: 16x28 = 448 blocks, double-buffered K-loop
    gemm_bt<true><<<16 * 28, 256, 0, stream>>>(qkv_buf, wo_bf, nullptr, d_out, 3584, 3584, 3584);
}